// Round 1
// baseline (1006.757 us; speedup 1.0000x reference)
//
#include <hip/hip_runtime.h>
#include <hip/hip_bf16.h>

#define DEVFN __device__ __forceinline__

constexpr int Bb = 4, Nn = 2048, Dd = 512, Hh = 8, DVv = 64, DOo = 512;

typedef short short8 __attribute__((ext_vector_type(8)));
typedef float f32x4 __attribute__((ext_vector_type(4)));

typedef __attribute__((address_space(1))) void GV;   // global
typedef __attribute__((address_space(3))) void LV;   // LDS

DEVFN unsigned short f32_bf16(float f) {
  unsigned u = __builtin_bit_cast(unsigned, f);
  u += 0x7fffu + ((u >> 16) & 1u);          // RNE
  return (unsigned short)(u >> 16);
}

DEVFN void barrier_raw() {
  asm volatile("" ::: "memory");
  __builtin_amdgcn_s_barrier();
  asm volatile("" ::: "memory");
}

template<int Nv> DEVFN void wait_vmcnt() {
  if constexpr (Nv == 0)      asm volatile("s_waitcnt vmcnt(0)"  ::: "memory");
  else if constexpr (Nv == 6) asm volatile("s_waitcnt vmcnt(6)"  ::: "memory");
  else if constexpr (Nv == 8) asm volatile("s_waitcnt vmcnt(8)"  ::: "memory");
  else if constexpr (Nv == 12)asm volatile("s_waitcnt vmcnt(12)" ::: "memory");
  else static_assert(Nv == 0 || Nv == 6 || Nv == 8 || Nv == 12, "bad vmcnt");
}
DEVFN void wait_lgkm0() { asm volatile("s_waitcnt lgkmcnt(0)" ::: "memory"); }

// Stage TOTAL bytes (multiple of 4096) into LDS. Linear LDS dest (required by
// global_load_lds), XOR-swizzled GLOBAL source so that a swizzled ds_read is
// conflict-free: LDS(row,blk) holds global(row, blk ^ (row&7)).
template<int ROWBYTES, int TOTAL>
DEVFN void stage_tile(const char* g, int strideBytes, char* lds, int tid) {
#pragma unroll
  for (int off = 0; off < TOTAL; off += 4096) {
    int o   = off + tid * 16;
    int row = o / ROWBYTES;
    int blk = (o >> 4) & ((ROWBYTES >> 4) - 1);
    int sb  = blk ^ (row & 7);
    const char* src = g + (size_t)row * strideBytes + (sb << 4);
    __builtin_amdgcn_global_load_lds((GV*)src, (LV*)(lds + o), 16, 0, 0);
  }
}

template<int ROWBYTES>
DEVFN short8 frag_ld(const char* lds, int row, int kbyte) {
  int blk = kbyte >> 4;
  int sb  = blk ^ (row & 7);
  return *(const short8*)(lds + row * ROWBYTES + (sb << 4));
}

DEVFN f32x4 mfma16(short8 a, short8 b, f32x4 c) {
  return __builtin_amdgcn_mfma_f32_16x16x32_bf16(a, b, c, 0, 0, 0);
}

// ---------------- small prep kernels ----------------

__global__ void cvt_f32_bf16_kernel(const float* __restrict__ in,
                                    unsigned short* __restrict__ out, int n4) {
  int i = blockIdx.x * blockDim.x + threadIdx.x;
  if (i < n4) {
    float4 v = ((const float4*)in)[i];
    ushort4 o;
    o.x = f32_bf16(v.x); o.y = f32_bf16(v.y);
    o.z = f32_bf16(v.z); o.w = f32_bf16(v.w);
    ((ushort4*)out)[i] = o;
  }
}

// in: [G][R][C] f32 -> out: [G][C][R] bf16
__global__ void transpose_w_kernel(const float* __restrict__ in,
                                   unsigned short* __restrict__ out, int R, int C) {
  __shared__ float t[32][33];
  int g = blockIdx.z;
  int c0 = blockIdx.x * 32, r0 = blockIdx.y * 32;
  const float* ip = in + (size_t)g * R * C;
  unsigned short* op = out + (size_t)g * R * C;
#pragma unroll
  for (int i = threadIdx.y; i < 32; i += 8)
    t[i][threadIdx.x] = ip[(size_t)(r0 + i) * C + c0 + threadIdx.x];
  __syncthreads();
#pragma unroll
  for (int i = threadIdx.y; i < 32; i += 8)
    op[(size_t)(c0 + i) * R + r0 + threadIdx.x] = f32_bf16(t[threadIdx.x][i]);
}

// in: [G][R][C] bf16 -> out: [G][C][R] bf16
__global__ void transpose_u16_kernel(const unsigned short* __restrict__ in,
                                     unsigned short* __restrict__ out, int R, int C) {
  __shared__ unsigned short t[32][33];
  int g = blockIdx.z;
  int c0 = blockIdx.x * 32, r0 = blockIdx.y * 32;
  const unsigned short* ip = in + (size_t)g * R * C;
  unsigned short* op = out + (size_t)g * R * C;
#pragma unroll
  for (int i = threadIdx.y; i < 32; i += 8)
    t[i][threadIdx.x] = ip[(size_t)(r0 + i) * C + c0 + threadIdx.x];
  __syncthreads();
#pragma unroll
  for (int i = threadIdx.y; i < 32; i += 8)
    op[(size_t)(c0 + i) * R + r0 + threadIdx.x] = t[threadIdx.x][i];
}

// ---------------- NT GEMM: C[M x Ncols] = A[M x 512] * Bt[Ncols x 512]^T ----------------
// A bf16 row-major (ld=512), Bt bf16 row-major (rows = output cols, ld=512).
// Output row addressing: orow = ((grow>>11)*HeadsOut + h)*2048 + (grow&2047).

template<int NCG, bool OUTF32>
__global__ __launch_bounds__(256)
void gemm_nt_kernel(const unsigned short* __restrict__ A,
                    const unsigned short* __restrict__ BtAll,
                    void* __restrict__ Cb, int HeadsOut, int Ncols) {
  constexpr int BN = NCG * 32;
  constexpr int NL = 4 + BN / 32;     // per-wave staged loads per k-step
  __shared__ alignas(16) char As[2][16384];
  __shared__ alignas(16) char Bs[2][BN * 128];
  int tid = threadIdx.x, lane = tid & 63;
  int w = tid >> 6, wr = w >> 1, wc = w & 1;
  int tM = blockIdx.x, tN = blockIdx.y, h = blockIdx.z;
  const char* Ab  = (const char*)A + ((size_t)tM * 128) * 1024;
  const char* Btb = (const char*)BtAll + ((size_t)h * Ncols + tN * BN) * 1024;

  f32x4 acc[4][NCG] = {};

  stage_tile<128, 16384>(Ab, 1024, As[0], tid);
  stage_tile<128, BN * 128>(Btb, 1024, Bs[0], tid);
#pragma unroll
  for (int kk = 0; kk < 8; ++kk) {
    int cur = kk & 1;
    if (kk < 7) {
      stage_tile<128, 16384>(Ab + (kk + 1) * 128, 1024, As[cur ^ 1], tid);
      stage_tile<128, BN * 128>(Btb + (kk + 1) * 128, 1024, Bs[cur ^ 1], tid);
      wait_vmcnt<NL>();
    } else {
      wait_vmcnt<0>();
    }
    barrier_raw();
#pragma unroll
    for (int c = 0; c < 2; ++c) {
      short8 af[4], bf[NCG];
#pragma unroll
      for (int rg = 0; rg < 4; ++rg)
        af[rg] = frag_ld<128>(As[cur], wr * 64 + rg * 16 + (lane & 15),
                              c * 64 + (lane >> 4) * 16);
#pragma unroll
      for (int cg = 0; cg < NCG; ++cg)
        bf[cg] = frag_ld<128>(Bs[cur], wc * (NCG * 16) + cg * 16 + (lane & 15),
                              c * 64 + (lane >> 4) * 16);
#pragma unroll
      for (int rg = 0; rg < 4; ++rg)
#pragma unroll
        for (int cg = 0; cg < NCG; ++cg)
          acc[rg][cg] = mfma16(af[rg], bf[cg], acc[rg][cg]);
    }
    barrier_raw();
  }

#pragma unroll
  for (int rg = 0; rg < 4; ++rg)
#pragma unroll
    for (int cg = 0; cg < NCG; ++cg)
#pragma unroll
      for (int r = 0; r < 4; ++r) {
        int grow = tM * 128 + wr * 64 + rg * 16 + (lane >> 4) * 4 + r;
        int col  = tN * BN + wc * (NCG * 16) + cg * 16 + (lane & 15);
        size_t orow = ((size_t)(grow >> 11) * HeadsOut + h) * 2048 + (grow & 2047);
        if constexpr (OUTF32)
          ((float*)Cb)[orow * Ncols + col] = acc[rg][cg][r];
        else
          ((unsigned short*)Cb)[orow * Ncols + col] = f32_bf16(acc[rg][cg][r]);
      }
}

// ---------------- fused masked-score + PV kernel ----------------
// Per block: (b, h, 128-row tile). For each of 16 column tiles:
//   S = Q*K^T (bf16 MFMA, f32 acc), masked+scaled -> attn_out (f32) and
//   Ss (bf16, swizzled LDS); O += S*V via V^T tile.  O -> QKV ws (bf16).

__global__ __launch_bounds__(256)
void attn_fused_kernel(const unsigned short* __restrict__ Qb,
                       const unsigned short* __restrict__ Kb,
                       const unsigned short* __restrict__ VbT,
                       const int* __restrict__ mask,
                       float* __restrict__ attn_out,
                       unsigned short* __restrict__ QKV) {
  __shared__ alignas(16) char Qs[2][16384];
  __shared__ alignas(16) char Ks[2][16384];
  __shared__ alignas(16) char Ss[32768];     // 128 x 128 bf16, 256 B rows
  __shared__ alignas(16) char Vt[16384];     // 64 x 128 bf16 (V^T tile)
  int tid = threadIdx.x, lane = tid & 63;
  int w = tid >> 6, wr = w >> 1, wc = w & 1;
  int mt = blockIdx.x, h = blockIdx.y, b = blockIdx.z;
  size_t bh = (size_t)b * Hh + h;
  const char* Qg  = (const char*)Qb + (bh * Nn + (size_t)mt * 128) * 1024;
  const char* Kg0 = (const char*)Kb + bh * Nn * 1024;
  const char* Vg0 = (const char*)VbT + bh * (size_t)DVv * Nn * 2;
  const float scale = 0.044194173824159216f;   // 1/sqrt(512)

  f32x4 oacc[2][4] = {};

  for (int j = 0; j < 16; ++j) {
    f32x4 sacc[4][4] = {};
    const char* Kg = Kg0 + (size_t)j * 128 * 1024;

    stage_tile<128, 16384>(Qg, 1024, Qs[0], tid);
    stage_tile<128, 16384>(Kg, 1024, Ks[0], tid);
#pragma unroll
    for (int kk = 0; kk < 8; ++kk) {
      int cur = kk & 1;
      if (kk < 7) {
        stage_tile<128, 16384>(Qg + (kk + 1) * 128, 1024, Qs[cur ^ 1], tid);
        stage_tile<128, 16384>(Kg + (kk + 1) * 128, 1024, Ks[cur ^ 1], tid);
        if (kk == 3) wait_vmcnt<12>();   // V^T tile sits in the queue
        else         wait_vmcnt<8>();
      } else {
        wait_vmcnt<0>();
      }
      barrier_raw();
      if (kk == 2)   // prefetch V^T tile; drained by kk=4's wait
        stage_tile<256, 16384>(Vg0 + j * 256, Nn * 2, Vt, tid);
#pragma unroll
      for (int c = 0; c < 2; ++c) {
        short8 af[4], bf[4];
#pragma unroll
        for (int rg = 0; rg < 4; ++rg)
          af[rg] = frag_ld<128>(Qs[cur], wr * 64 + rg * 16 + (lane & 15),
                                c * 64 + (lane >> 4) * 16);
#pragma unroll
        for (int cg = 0; cg < 4; ++cg)
          bf[cg] = frag_ld<128>(Ks[cur], wc * 64 + cg * 16 + (lane & 15),
                                c * 64 + (lane >> 4) * 16);
#pragma unroll
        for (int rg = 0; rg < 4; ++rg)
#pragma unroll
          for (int cg = 0; cg < 4; ++cg)
            sacc[rg][cg] = mfma16(af[rg], bf[cg], sacc[rg][cg]);
      }
      barrier_raw();
    }

    // mask + scale; write attn (f32, d_out) and Ss (bf16, swizzled LDS)
    float* attn_tile = attn_out + (bh * Nn + (size_t)mt * 128) * Nn + j * 128;
#pragma unroll
    for (int rg = 0; rg < 4; ++rg)
#pragma unroll
      for (int cg = 0; cg < 4; ++cg)
#pragma unroll
        for (int r = 0; r < 4; ++r) {
          int rowL = wr * 64 + rg * 16 + (lane >> 4) * 4 + r;
          int colL = wc * 64 + cg * 16 + (lane & 15);
          int grow = mt * 128 + rowL, gcol = j * 128 + colL;
          int mv = mask[(size_t)grow * Nn + gcol];
          float vv = mv ? 0.0f : sacc[rg][cg][r] * scale;
          attn_tile[(size_t)rowL * Nn + colL] = vv;
          int byte = rowL * 256 + colL * 2;
          byte ^= (rowL & 7) << 4;
          *(unsigned short*)(Ss + byte) = f32_bf16(vv);
        }
    wait_lgkm0();       // Ss ds_writes visible (V^T already vmcnt-drained)
    barrier_raw();

    // O += S * V : A = Ss rows (this wave: rows w*32..w*32+31), B = Vt
#pragma unroll
    for (int mc = 0; mc < 4; ++mc) {
      short8 af2[2], bf2[4];
#pragma unroll
      for (int rg = 0; rg < 2; ++rg)
        af2[rg] = frag_ld<256>(Ss, w * 32 + rg * 16 + (lane & 15),
                               mc * 64 + (lane >> 4) * 16);
#pragma unroll
      for (int cg = 0; cg < 4; ++cg)
        bf2[cg] = frag_ld<256>(Vt, cg * 16 + (lane & 15),
                               mc * 64 + (lane >> 4) * 16);
#pragma unroll
      for (int rg = 0; rg < 2; ++rg)
#pragma unroll
        for (int cg = 0; cg < 4; ++cg)
          oacc[rg][cg] = mfma16(af2[rg], bf2[cg], oacc[rg][cg]);
    }
    // no trailing barrier needed: next j's first overwrite of Ss/Vt is
    // several barriers away; Qs/Ks staging doesn't touch Ss/Vt.
  }

  // write O -> QKV[b][n][h*64+v] bf16
#pragma unroll
  for (int rg = 0; rg < 2; ++rg)
#pragma unroll
    for (int cg = 0; cg < 4; ++cg)
#pragma unroll
      for (int r = 0; r < 4; ++r) {
        int rowL = w * 32 + rg * 16 + (lane >> 4) * 4 + r;
        size_t grow = (size_t)mt * 128 + rowL;
        int col = cg * 16 + (lane & 15);
        QKV[((size_t)b * Nn + grow) * (Hh * DVv) + h * DVv + col] =
            f32_bf16(oacc[rg][cg][r]);
      }
}

// ---------------- host ----------------

extern "C" void kernel_launch(void* const* d_in, const int* in_sizes, int n_in,
                              void* d_out, int out_size, void* d_ws, size_t ws_size,
                              hipStream_t stream) {
  const float* q    = (const float*)d_in[0];
  const float* k    = (const float*)d_in[1];
  const float* v    = (const float*)d_in[2];
  const int*   mask = (const int*)d_in[3];
  const float* Wq   = (const float*)d_in[4];
  const float* Wk   = (const float*)d_in[5];
  const float* Wv   = (const float*)d_in[6];
  const float* Wo   = (const float*)d_in[7];

  char* ws = (char*)d_ws;
  size_t off = 0;
  auto alloc = [&](size_t bytes) {
    char* p = ws + off;
    off += (bytes + 255) & ~(size_t)255;
    return p;
  };
  unsigned short* WqT  = (unsigned short*)alloc((size_t)Hh * Dd * Dd * 2);
  unsigned short* WkT  = (unsigned short*)alloc((size_t)Hh * Dd * Dd * 2);
  unsigned short* WvT  = (unsigned short*)alloc((size_t)Hh * DVv * Dd * 2);
  unsigned short* WoT  = (unsigned short*)alloc((size_t)DOo * Hh * DVv * 2);
  unsigned short* Xq   = (unsigned short*)alloc((size_t)Bb * Nn * Dd * 2);
  unsigned short* Xk   = (unsigned short*)alloc((size_t)Bb * Nn * Dd * 2);
  unsigned short* Xv   = (unsigned short*)alloc((size_t)Bb * Nn * Dd * 2);
  unsigned short* Qb   = (unsigned short*)alloc((size_t)Bb * Hh * Nn * Dd * 2);
  unsigned short* Kb   = (unsigned short*)alloc((size_t)Bb * Hh * Nn * Dd * 2);
  unsigned short* Vb   = (unsigned short*)alloc((size_t)Bb * Hh * Nn * DVv * 2);
  unsigned short* VbT  = (unsigned short*)alloc((size_t)Bb * Hh * DVv * Nn * 2);
  unsigned short* QKVb = (unsigned short*)alloc((size_t)Bb * Nn * Hh * DVv * 2);

  int n4 = Bb * Nn * Dd / 4;
  cvt_f32_bf16_kernel<<<dim3(n4 / 256), dim3(256), 0, stream>>>(q, Xq, n4);
  cvt_f32_bf16_kernel<<<dim3(n4 / 256), dim3(256), 0, stream>>>(k, Xk, n4);
  cvt_f32_bf16_kernel<<<dim3(n4 / 256), dim3(256), 0, stream>>>(v, Xv, n4);

  transpose_w_kernel<<<dim3(Dd / 32, Dd / 32, Hh), dim3(32, 8), 0, stream>>>(Wq, WqT, Dd, Dd);
  transpose_w_kernel<<<dim3(Dd / 32, Dd / 32, Hh), dim3(32, 8), 0, stream>>>(Wk, WkT, Dd, Dd);
  transpose_w_kernel<<<dim3(DVv / 32, Dd / 32, Hh), dim3(32, 8), 0, stream>>>(Wv, WvT, Dd, DVv);
  transpose_w_kernel<<<dim3(DOo / 32, (Hh * DVv) / 32, 1), dim3(32, 8), 0, stream>>>(Wo, WoT, Hh * DVv, DOo);

  gemm_nt_kernel<4, false><<<dim3(64, 4, Hh), dim3(256), 0, stream>>>(Xq, WqT, Qb, Hh, Dd);
  gemm_nt_kernel<4, false><<<dim3(64, 4, Hh), dim3(256), 0, stream>>>(Xk, WkT, Kb, Hh, Dd);
  gemm_nt_kernel<2, false><<<dim3(64, 1, Hh), dim3(256), 0, stream>>>(Xv, WvT, Vb, Hh, DVv);

  transpose_u16_kernel<<<dim3(DVv / 32, Nn / 32, Bb * Hh), dim3(32, 8), 0, stream>>>(Vb, VbT, Nn, DVv);

  float* outp  = (float*)d_out;
  float* attnp = outp + (size_t)Bb * Nn * DOo;
  attn_fused_kernel<<<dim3(Nn / 128, Hh, Bb), dim3(256), 0, stream>>>(Qb, Kb, VbT, mask, attnp, QKVb);

  gemm_nt_kernel<4, true><<<dim3(64, 4, 1), dim3(256), 0, stream>>>(QKVb, WoT, outp, 1, DOo);

  (void)in_sizes; (void)n_in; (void)out_size; (void)ws_size;
}

// Round 2
// 602.993 us; speedup vs baseline: 1.6696x; 1.6696x over previous
//
#include <hip/hip_runtime.h>
#include <hip/hip_bf16.h>

#define DEVFN __device__ __forceinline__

constexpr int Bb = 4, Nn = 2048, Dd = 512, Hh = 8, DVv = 64, DOo = 512;

typedef short short8 __attribute__((ext_vector_type(8)));
typedef float f32x4 __attribute__((ext_vector_type(4)));

typedef __attribute__((address_space(1))) void GV;   // global
typedef __attribute__((address_space(3))) void LV;   // LDS

DEVFN unsigned short f32_bf16(float f) {
  unsigned u = __builtin_bit_cast(unsigned, f);
  u += 0x7fffu + ((u >> 16) & 1u);          // RNE
  return (unsigned short)(u >> 16);
}

DEVFN void barrier_raw() {
  asm volatile("" ::: "memory");
  __builtin_amdgcn_s_barrier();
  asm volatile("" ::: "memory");
}

template<int Nv> DEVFN void wait_vmcnt() {
  if constexpr (Nv == 0)      asm volatile("s_waitcnt vmcnt(0)"  ::: "memory");
  else if constexpr (Nv == 6) asm volatile("s_waitcnt vmcnt(6)"  ::: "memory");
  else if constexpr (Nv == 8) asm volatile("s_waitcnt vmcnt(8)"  ::: "memory");
  else static_assert(Nv == 0 || Nv == 6 || Nv == 8, "bad vmcnt");
}
DEVFN void wait_lgkm0() { asm volatile("s_waitcnt lgkmcnt(0)" ::: "memory"); }

// Stage TOTAL bytes (multiple of 4096) into LDS. Linear LDS dest (required by
// global_load_lds), XOR-swizzled GLOBAL source so that a swizzled ds_read is
// conflict-free: LDS(row,blk) holds global(row, blk ^ (row&7)).
template<int ROWBYTES, int TOTAL>
DEVFN void stage_tile(const char* g, int strideBytes, char* lds, int tid) {
#pragma unroll
  for (int off = 0; off < TOTAL; off += 4096) {
    int o   = off + tid * 16;
    int row = o / ROWBYTES;
    int blk = (o >> 4) & ((ROWBYTES >> 4) - 1);
    int sb  = blk ^ (row & 7);
    const char* src = g + (size_t)row * strideBytes + (sb << 4);
    __builtin_amdgcn_global_load_lds((GV*)src, (LV*)(lds + o), 16, 0, 0);
  }
}

template<int ROWBYTES>
DEVFN short8 frag_ld(const char* lds, int row, int kbyte) {
  int blk = kbyte >> 4;
  int sb  = blk ^ (row & 7);
  return *(const short8*)(lds + row * ROWBYTES + (sb << 4));
}

DEVFN f32x4 mfma16(short8 a, short8 b, f32x4 c) {
  return __builtin_amdgcn_mfma_f32_16x16x32_bf16(a, b, c, 0, 0, 0);
}

// ---------------- small prep kernels ----------------

__global__ void cvt_f32_bf16_kernel(const float* __restrict__ in,
                                    unsigned short* __restrict__ out, int n4) {
  int i = blockIdx.x * blockDim.x + threadIdx.x;
  if (i < n4) {
    float4 v = ((const float4*)in)[i];
    ushort4 o;
    o.x = f32_bf16(v.x); o.y = f32_bf16(v.y);
    o.z = f32_bf16(v.z); o.w = f32_bf16(v.w);
    ((ushort4*)out)[i] = o;
  }
}

// mask int32 {0,1} -> bf16 keep {1.0, 0.0}
__global__ void mask_prep_kernel(const int* __restrict__ m,
                                 unsigned short* __restrict__ ms, int n4) {
  int i = blockIdx.x * blockDim.x + threadIdx.x;
  if (i < n4) {
    int4 v = ((const int4*)m)[i];
    ushort4 o;
    o.x = v.x ? 0 : 0x3f80; o.y = v.y ? 0 : 0x3f80;
    o.z = v.z ? 0 : 0x3f80; o.w = v.w ? 0 : 0x3f80;
    ((ushort4*)ms)[i] = o;
  }
}

// in: [G][R][C] f32 -> out: [G][C][R] bf16
__global__ void transpose_w_kernel(const float* __restrict__ in,
                                   unsigned short* __restrict__ out, int R, int C) {
  __shared__ float t[32][33];
  int g = blockIdx.z;
  int c0 = blockIdx.x * 32, r0 = blockIdx.y * 32;
  const float* ip = in + (size_t)g * R * C;
  unsigned short* op = out + (size_t)g * R * C;
#pragma unroll
  for (int i = threadIdx.y; i < 32; i += 8)
    t[i][threadIdx.x] = ip[(size_t)(r0 + i) * C + c0 + threadIdx.x];
  __syncthreads();
#pragma unroll
  for (int i = threadIdx.y; i < 32; i += 8)
    op[(size_t)(c0 + i) * R + r0 + threadIdx.x] = f32_bf16(t[threadIdx.x][i]);
}

// in: [G][R][C] bf16 -> out: [G][C][R] bf16
__global__ void transpose_u16_kernel(const unsigned short* __restrict__ in,
                                     unsigned short* __restrict__ out, int R, int C) {
  __shared__ unsigned short t[32][33];
  int g = blockIdx.z;
  int c0 = blockIdx.x * 32, r0 = blockIdx.y * 32;
  const unsigned short* ip = in + (size_t)g * R * C;
  unsigned short* op = out + (size_t)g * R * C;
#pragma unroll
  for (int i = threadIdx.y; i < 32; i += 8)
    t[i][threadIdx.x] = ip[(size_t)(r0 + i) * C + c0 + threadIdx.x];
  __syncthreads();
#pragma unroll
  for (int i = threadIdx.y; i < 32; i += 8)
    op[(size_t)(c0 + i) * R + r0 + threadIdx.x] = t[threadIdx.x][i];
}

// ---------------- NT GEMM: C[M x Ncols] = A[M x 512] * Bt[Ncols x 512]^T ----------------

template<int NCG, bool OUTF32>
__global__ __launch_bounds__(256)
void gemm_nt_kernel(const unsigned short* __restrict__ A,
                    const unsigned short* __restrict__ BtAll,
                    void* __restrict__ Cb, int HeadsOut, int Ncols) {
  constexpr int BN = NCG * 32;
  constexpr int NL = 4 + BN / 32;     // per-thread staged loads per k-step
  __shared__ alignas(16) char As[2][16384];
  __shared__ alignas(16) char Bs[2][BN * 128];
  int tid = threadIdx.x, lane = tid & 63;
  int w = tid >> 6, wr = w >> 1, wc = w & 1;
  int tM = blockIdx.x, tN = blockIdx.y, h = blockIdx.z;
  const char* Ab  = (const char*)A + ((size_t)tM * 128) * 1024;
  const char* Btb = (const char*)BtAll + ((size_t)h * Ncols + tN * BN) * 1024;

  f32x4 acc[4][NCG] = {};

  stage_tile<128, 16384>(Ab, 1024, As[0], tid);
  stage_tile<128, BN * 128>(Btb, 1024, Bs[0], tid);
#pragma unroll
  for (int kk = 0; kk < 8; ++kk) {
    int cur = kk & 1;
    if (kk < 7) {
      stage_tile<128, 16384>(Ab + (kk + 1) * 128, 1024, As[cur ^ 1], tid);
      stage_tile<128, BN * 128>(Btb + (kk + 1) * 128, 1024, Bs[cur ^ 1], tid);
      wait_vmcnt<NL>();
    } else {
      wait_vmcnt<0>();
    }
    barrier_raw();
#pragma unroll
    for (int c = 0; c < 2; ++c) {
      short8 af[4], bf[NCG];
#pragma unroll
      for (int rg = 0; rg < 4; ++rg)
        af[rg] = frag_ld<128>(As[cur], wr * 64 + rg * 16 + (lane & 15),
                              c * 64 + (lane >> 4) * 16);
#pragma unroll
      for (int cg = 0; cg < NCG; ++cg)
        bf[cg] = frag_ld<128>(Bs[cur], wc * (NCG * 16) + cg * 16 + (lane & 15),
                              c * 64 + (lane >> 4) * 16);
#pragma unroll
      for (int rg = 0; rg < 4; ++rg)
#pragma unroll
        for (int cg = 0; cg < NCG; ++cg)
          acc[rg][cg] = mfma16(af[rg], bf[cg], acc[rg][cg]);
    }
    barrier_raw();
  }

#pragma unroll
  for (int rg = 0; rg < 4; ++rg)
#pragma unroll
    for (int cg = 0; cg < NCG; ++cg)
#pragma unroll
      for (int r = 0; r < 4; ++r) {
        int grow = tM * 128 + wr * 64 + rg * 16 + (lane >> 4) * 4 + r;
        int col  = tN * BN + wc * (NCG * 16) + cg * 16 + (lane & 15);
        size_t orow = ((size_t)(grow >> 11) * HeadsOut + h) * 2048 + (grow & 2047);
        if constexpr (OUTF32)
          ((float*)Cb)[orow * Ncols + col] = acc[rg][cg][r];
        else
          ((unsigned short*)Cb)[orow * Ncols + col] = f32_bf16(acc[rg][cg][r]);
      }
}

// ---------------- S = Q*K^T + mask + scale -> attn f32 (d_out) ----------------
// One block per 128x128 S-tile. Grid: 8192 blocks 1-D, XCD-chunked swizzle.

__global__ __launch_bounds__(256)
void qk_attn_kernel(const unsigned short* __restrict__ Qb,
                    const unsigned short* __restrict__ Kb,
                    const unsigned short* __restrict__ ms,
                    float* __restrict__ attn_out) {
  __shared__ alignas(16) char As[2][16384];
  __shared__ alignas(16) char Bs[2][16384];
  int tid = threadIdx.x, lane = tid & 63;
  int w = tid >> 6, wr = w >> 1, wc = w & 1;
  int fid = blockIdx.x;
  int orig = (fid & 7) * 1024 + (fid >> 3);     // XCD-chunked (8192 % 8 == 0)
  int tM = orig & 15, tN = (orig >> 4) & 15, bh = orig >> 8;

  const char* Ab  = (const char*)Qb + ((size_t)bh * Nn + tM * 128) * 1024;
  const char* Btb = (const char*)Kb + ((size_t)bh * Nn + tN * 128) * 1024;
  const float scale = 0.044194173824159216f;   // 1/sqrt(512)

  f32x4 acc[4][4] = {};

  stage_tile<128, 16384>(Ab, 1024, As[0], tid);
  stage_tile<128, 16384>(Btb, 1024, Bs[0], tid);
#pragma unroll
  for (int kk = 0; kk < 8; ++kk) {
    int cur = kk & 1;
    if (kk < 7) {
      stage_tile<128, 16384>(Ab + (kk + 1) * 128, 1024, As[cur ^ 1], tid);
      stage_tile<128, 16384>(Btb + (kk + 1) * 128, 1024, Bs[cur ^ 1], tid);
      wait_vmcnt<8>();
    } else {
      wait_vmcnt<0>();
    }
    barrier_raw();
#pragma unroll
    for (int c = 0; c < 2; ++c) {
      short8 af[4], bf[4];
#pragma unroll
      for (int rg = 0; rg < 4; ++rg)
        af[rg] = frag_ld<128>(As[cur], wr * 64 + rg * 16 + (lane & 15),
                              c * 64 + (lane >> 4) * 16);
#pragma unroll
      for (int cg = 0; cg < 4; ++cg)
        bf[cg] = frag_ld<128>(Bs[cur], wc * 64 + cg * 16 + (lane & 15),
                              c * 64 + (lane >> 4) * 16);
#pragma unroll
      for (int rg = 0; rg < 4; ++rg)
#pragma unroll
        for (int cg = 0; cg < 4; ++cg)
          acc[rg][cg] = mfma16(af[rg], bf[cg], acc[rg][cg]);
    }
    barrier_raw();
  }

  // epilogue: vv = acc * scale * keep ; write attn f32
#pragma unroll
  for (int rg = 0; rg < 4; ++rg)
#pragma unroll
    for (int cg = 0; cg < 4; ++cg)
#pragma unroll
      for (int r = 0; r < 4; ++r) {
        int rowL = wr * 64 + rg * 16 + (lane >> 4) * 4 + r;
        int colL = wc * 64 + cg * 16 + (lane & 15);
        int qrow = tM * 128 + rowL, kcol = tN * 128 + colL;
        unsigned short kv = ms[(size_t)qrow * Nn + kcol];
        float keep = __builtin_bit_cast(float, (unsigned)kv << 16);
        attn_out[((size_t)bh * Nn + qrow) * Nn + kcol] =
            acc[rg][cg][r] * scale * keep;
      }
}

// ---------------- O = S * V  (S f32 from d_out, V^T bf16) ----------------
// Per (bh): C[2048 x 64] = S[2048 x 2048] * VbT[64 x 2048]^T. Tile 128x64,
// BK=64, 32 k-steps. A reg-staged f32->bf16 into swizzled LDS; B global_load_lds.

__global__ __launch_bounds__(256)
void pv_kernel(const float* __restrict__ attn,
               const unsigned short* __restrict__ VbT,
               unsigned short* __restrict__ QKV) {
  __shared__ alignas(16) char As[2][16384];   // 128 x 64 bf16 (swizzled)
  __shared__ alignas(16) char Bs[2][8192];    // 64 x 64 bf16 (swizzled)
  int tid = threadIdx.x, lane = tid & 63;
  int w = tid >> 6, wr = w >> 1, wc = w & 1;
  int tM = blockIdx.x, bh = blockIdx.y;
  int b = bh >> 3, h = bh & 7;

  int arow = tid >> 1, ahalf = tid & 1;       // this thread's A-stage slice
  const float* Ag = attn + ((size_t)bh * Nn + (size_t)tM * 128 + arow) * Nn
                    + ahalf * 32;
  const char* Btb = (const char*)VbT + (size_t)bh * DVv * Nn * 2;

  f32x4 acc[4][2] = {};

  // prologue: stage tile 0
  {
    float4 ar[8];
#pragma unroll
    for (int i = 0; i < 8; ++i) ar[i] = ((const float4*)Ag)[i];
    stage_tile<128, 8192>(Btb, Nn * 2, Bs[0], tid);
    wait_vmcnt<0>();
#pragma unroll
    for (int j = 0; j < 4; ++j) {
      short8 s;
#pragma unroll
      for (int e = 0; e < 4; ++e) {
        s[e]     = (short)f32_bf16(ar[2 * j][e]);
        s[e + 4] = (short)f32_bf16(ar[2 * j + 1][e]);
      }
      int sb = (ahalf * 4 + j) ^ (arow & 7);
      *(short8*)(As[0] + arow * 128 + (sb << 4)) = s;
    }
    wait_lgkm0();
    barrier_raw();
  }

#pragma unroll 2
  for (int kk = 0; kk < 32; ++kk) {
    int cur = kk & 1;
    float4 ar[8];
    if (kk < 31) {
      const float* an = Ag + (kk + 1) * 64;
#pragma unroll
      for (int i = 0; i < 8; ++i) ar[i] = ((const float4*)an)[i];
      stage_tile<128, 8192>(Btb + (kk + 1) * 128, Nn * 2, Bs[cur ^ 1], tid);
    }
#pragma unroll
    for (int c = 0; c < 2; ++c) {
      short8 af[4], bf2[2];
#pragma unroll
      for (int rg = 0; rg < 4; ++rg)
        af[rg] = frag_ld<128>(As[cur], wr * 64 + rg * 16 + (lane & 15),
                              c * 64 + (lane >> 4) * 16);
#pragma unroll
      for (int cg = 0; cg < 2; ++cg)
        bf2[cg] = frag_ld<128>(Bs[cur], wc * 32 + cg * 16 + (lane & 15),
                               c * 64 + (lane >> 4) * 16);
#pragma unroll
      for (int rg = 0; rg < 4; ++rg)
#pragma unroll
        for (int cg = 0; cg < 2; ++cg)
          acc[rg][cg] = mfma16(af[rg], bf2[cg], acc[rg][cg]);
    }
    if (kk < 31) {
      wait_vmcnt<0>();         // A regs + B LDS landed
#pragma unroll
      for (int j = 0; j < 4; ++j) {
        short8 s;
#pragma unroll
        for (int e = 0; e < 4; ++e) {
          s[e]     = (short)f32_bf16(ar[2 * j][e]);
          s[e + 4] = (short)f32_bf16(ar[2 * j + 1][e]);
        }
        int sb = (ahalf * 4 + j) ^ (arow & 7);
        *(short8*)(As[cur ^ 1] + arow * 128 + (sb << 4)) = s;
      }
      wait_lgkm0();
    }
    barrier_raw();
  }

  // write O -> QKV[b][n][h*64+v] bf16
#pragma unroll
  for (int rg = 0; rg < 4; ++rg)
#pragma unroll
    for (int cg = 0; cg < 2; ++cg)
#pragma unroll
      for (int r = 0; r < 4; ++r) {
        int rowL = wr * 64 + rg * 16 + (lane >> 4) * 4 + r;
        int colL = wc * 32 + cg * 16 + (lane & 15);
        size_t grow = (size_t)tM * 128 + rowL;
        QKV[((size_t)b * Nn + grow) * (Hh * DVv) + h * DVv + colL] =
            f32_bf16(acc[rg][cg][r]);
      }
}

// ---------------- host ----------------

extern "C" void kernel_launch(void* const* d_in, const int* in_sizes, int n_in,
                              void* d_out, int out_size, void* d_ws, size_t ws_size,
                              hipStream_t stream) {
  const float* q    = (const float*)d_in[0];
  const float* k    = (const float*)d_in[1];
  const float* v    = (const float*)d_in[2];
  const int*   mask = (const int*)d_in[3];
  const float* Wq   = (const float*)d_in[4];
  const float* Wk   = (const float*)d_in[5];
  const float* Wv   = (const float*)d_in[6];
  const float* Wo   = (const float*)d_in[7];

  char* ws = (char*)d_ws;
  size_t off = 0;
  auto alloc = [&](size_t bytes) {
    char* p = ws + off;
    off += (bytes + 255) & ~(size_t)255;
    return p;
  };
  unsigned short* WqT  = (unsigned short*)alloc((size_t)Hh * Dd * Dd * 2);
  unsigned short* WkT  = (unsigned short*)alloc((size_t)Hh * Dd * Dd * 2);
  unsigned short* WvT  = (unsigned short*)alloc((size_t)Hh * DVv * Dd * 2);
  unsigned short* WoT  = (unsigned short*)alloc((size_t)DOo * Hh * DVv * 2);
  unsigned short* Xq   = (unsigned short*)alloc((size_t)Bb * Nn * Dd * 2);
  unsigned short* Xk   = (unsigned short*)alloc((size_t)Bb * Nn * Dd * 2);
  unsigned short* Xv   = (unsigned short*)alloc((size_t)Bb * Nn * Dd * 2);
  unsigned short* Qb   = (unsigned short*)alloc((size_t)Bb * Hh * Nn * Dd * 2);
  unsigned short* Kb   = (unsigned short*)alloc((size_t)Bb * Hh * Nn * Dd * 2);
  unsigned short* Vb   = (unsigned short*)alloc((size_t)Bb * Hh * Nn * DVv * 2);
  unsigned short* VbT  = (unsigned short*)alloc((size_t)Bb * Hh * DVv * Nn * 2);
  unsigned short* QKVb = (unsigned short*)alloc((size_t)Bb * Nn * Hh * DVv * 2);
  unsigned short* Ms   = (unsigned short*)alloc((size_t)Nn * Nn * 2);

  int n4 = Bb * Nn * Dd / 4;
  cvt_f32_bf16_kernel<<<dim3(n4 / 256), dim3(256), 0, stream>>>(q, Xq, n4);
  cvt_f32_bf16_kernel<<<dim3(n4 / 256), dim3(256), 0, stream>>>(k, Xk, n4);
  cvt_f32_bf16_kernel<<<dim3(n4 / 256), dim3(256), 0, stream>>>(v, Xv, n4);
  mask_prep_kernel<<<dim3(Nn * Nn / 4 / 256), dim3(256), 0, stream>>>(mask, Ms, Nn * Nn / 4);

  transpose_w_kernel<<<dim3(Dd / 32, Dd / 32, Hh), dim3(32, 8), 0, stream>>>(Wq, WqT, Dd, Dd);
  transpose_w_kernel<<<dim3(Dd / 32, Dd / 32, Hh), dim3(32, 8), 0, stream>>>(Wk, WkT, Dd, Dd);
  transpose_w_kernel<<<dim3(DVv / 32, Dd / 32, Hh), dim3(32, 8), 0, stream>>>(Wv, WvT, Dd, DVv);
  transpose_w_kernel<<<dim3(DOo / 32, (Hh * DVv) / 32, 1), dim3(32, 8), 0, stream>>>(Wo, WoT, Hh * DVv, DOo);

  gemm_nt_kernel<4, false><<<dim3(64, 4, Hh), dim3(256), 0, stream>>>(Xq, WqT, Qb, Hh, Dd);
  gemm_nt_kernel<4, false><<<dim3(64, 4, Hh), dim3(256), 0, stream>>>(Xk, WkT, Kb, Hh, Dd);
  gemm_nt_kernel<2, false><<<dim3(64, 1, Hh), dim3(256), 0, stream>>>(Xv, WvT, Vb, Hh, DVv);

  transpose_u16_kernel<<<dim3(DVv / 32, Nn / 32, Bb * Hh), dim3(32, 8), 0, stream>>>(Vb, VbT, Nn, DVv);

  float* outp  = (float*)d_out;
  float* attnp = outp + (size_t)Bb * Nn * DOo;

  qk_attn_kernel<<<dim3(16 * 16 * Bb * Hh), dim3(256), 0, stream>>>(Qb, Kb, Ms, attnp);
  pv_kernel<<<dim3(16, Bb * Hh), dim3(256), 0, stream>>>(attnp, VbT, QKVb);

  gemm_nt_kernel<4, true><<<dim3(64, 4, 1), dim3(256), 0, stream>>>(QKVb, WoT, outp, 1, DOo);

  (void)in_sizes; (void)n_in; (void)out_size; (void)ws_size;
}